// Round 1
// baseline (253.130 us; speedup 1.0000x reference)
//
#include <hip/hip_runtime.h>
#include <math.h>

// LSQ quantizer with Hadamard rotation, done via fast Walsh-Hadamard transform.
//
// Identity used: H = H_sylvester * diag(signs) / sqrt(D), H_sylvester symmetric,
// H[0,j] = signs[j]/sqrt(D) =: h0[j].  Hence:
//   x @ H      = FWHT(x) .* h0
//   y @ H^T    = FWHT(y .* h0)
// so the whole op is per-row: FWHT -> elementwise quant -> FWHT, needing only
// row 0 of the hadamard input.

constexpr int D  = 2048;
constexpr int NR = 8;   // float4 registers per lane: 8 * 4 * 64 lanes = 2048

__device__ __forceinline__ void fwht2048(float4 (&v)[NR], int lane) {
    // --- in-register stages over the two low bits (j-strides 1, 2) ---
    #pragma unroll
    for (int r = 0; r < NR; ++r) {
        float a, b;
        a = v[r].x; b = v[r].y; v[r].x = a + b; v[r].y = a - b;   // stride 1
        a = v[r].z; b = v[r].w; v[r].z = a + b; v[r].w = a - b;
        a = v[r].x; b = v[r].z; v[r].x = a + b; v[r].z = a - b;   // stride 2
        a = v[r].y; b = v[r].w; v[r].y = a + b; v[r].w = a - b;
    }
    // --- cross-lane stages (j-strides 4..128 -> lane masks 1..32) ---
    #pragma unroll
    for (int m = 1; m <= 32; m <<= 1) {
        const float sgn = (lane & m) ? -1.0f : 1.0f;
        #pragma unroll
        for (int r = 0; r < NR; ++r) {
            float ox = __shfl_xor(v[r].x, m, 64);
            float oy = __shfl_xor(v[r].y, m, 64);
            float oz = __shfl_xor(v[r].z, m, 64);
            float ow = __shfl_xor(v[r].w, m, 64);
            // low lane (bit==0): a+b ; high lane (bit==1): a-b = other - own
            v[r].x = fmaf(sgn, v[r].x, ox);
            v[r].y = fmaf(sgn, v[r].y, oy);
            v[r].z = fmaf(sgn, v[r].z, oz);
            v[r].w = fmaf(sgn, v[r].w, ow);
        }
    }
    // --- in-register stages over the r4 bits (j-strides 256, 512, 1024) ---
    #pragma unroll
    for (int m = 1; m <= 4; m <<= 1) {
        #pragma unroll
        for (int r = 0; r < NR; ++r) {
            if ((r & m) == 0) {
                float4 a = v[r], b = v[r | m];
                v[r].x     = a.x + b.x; v[r].y     = a.y + b.y;
                v[r].z     = a.z + b.z; v[r].w     = a.w + b.w;
                v[r | m].x = a.x - b.x; v[r | m].y = a.y - b.y;
                v[r | m].z = a.z - b.z; v[r | m].w = a.w - b.w;
            }
        }
    }
}

__device__ __forceinline__ float quant1(float xh, float h0, float s, float inv_s,
                                        float nqn, float qp) {
    float t = xh * h0;                       // x_rot element
    float u = t * inv_s;                     // / s
    u = fminf(fmaxf(u, nqn), qp);            // clip(-Qn, Qp)
    float q = rintf(u);                      // round half-to-even (jnp.round)
    return q * (s * h0);                     // * s, then fold second h0 multiply
}

__global__ __launch_bounds__(256) void lsq_fwht_kernel(
    const float* __restrict__ x,
    const float* __restrict__ scale,
    const float* __restrict__ hadamard,
    const int*   __restrict__ qn_p,
    const int*   __restrict__ qp_p,
    const int*   __restrict__ ne_p,
    float*       __restrict__ out,
    int rows)
{
    const int lane = threadIdx.x & 63;
    const int wave = threadIdx.x >> 6;
    const int row  = blockIdx.x * 4 + wave;   // one wave per row
    if (row >= rows) return;                  // wave-uniform exit

    // scalar params — replicate reference fp32 rounding of the LSQ scale trick
    const float sc    = scale[0];
    const float qp    = (float)qp_p[0];
    const float nqn   = -(float)qn_p[0];
    const float gs    = 1.0f / sqrtf((float)ne_p[0] * qp);
    const float bw    = sc * gs;
    const float s     = (sc - bw) + bw;       // forward value == scale
    const float inv_s = 1.0f / s;

    // element j held by this lane at (r, c): j = r*256 + lane*4 + c
    float4 v[NR], h[NR];
    {
        const float4* x4 = reinterpret_cast<const float4*>(x + (size_t)row * D) + lane;
        const float4* h4 = reinterpret_cast<const float4*>(hadamard) + lane; // row 0
        #pragma unroll
        for (int r = 0; r < NR; ++r) {
            v[r] = x4[(size_t)r * 64];
            h[r] = h4[(size_t)r * 64];
        }
    }

    fwht2048(v, lane);

    #pragma unroll
    for (int r = 0; r < NR; ++r) {
        v[r].x = quant1(v[r].x, h[r].x, s, inv_s, nqn, qp);
        v[r].y = quant1(v[r].y, h[r].y, s, inv_s, nqn, qp);
        v[r].z = quant1(v[r].z, h[r].z, s, inv_s, nqn, qp);
        v[r].w = quant1(v[r].w, h[r].w, s, inv_s, nqn, qp);
    }

    fwht2048(v, lane);

    {
        float4* y4 = reinterpret_cast<float4*>(out + (size_t)row * D) + lane;
        #pragma unroll
        for (int r = 0; r < NR; ++r) y4[(size_t)r * 64] = v[r];
    }
}

extern "C" void kernel_launch(void* const* d_in, const int* in_sizes, int n_in,
                              void* d_out, int out_size, void* d_ws, size_t ws_size,
                              hipStream_t stream) {
    const float* x        = (const float*)d_in[0];
    const float* scale    = (const float*)d_in[1];
    const float* hadamard = (const float*)d_in[2];
    const int*   Qn       = (const int*)d_in[3];
    const int*   Qp       = (const int*)d_in[4];
    const int*   ne       = (const int*)d_in[5];
    float*       out      = (float*)d_out;

    const int rows = in_sizes[0] / D;                 // 16384 for B=4,S=4096
    const int grid = (rows + 3) / 4;                  // 4 waves (rows) per block

    lsq_fwht_kernel<<<grid, 256, 0, stream>>>(x, scale, hadamard, Qn, Qp, ne,
                                              out, rows);
}

// Round 2
// 247.197 us; speedup vs baseline: 1.0240x; 1.0240x over previous
//
#include <hip/hip_runtime.h>
#include <math.h>

// LSQ quantizer with Hadamard rotation via FWHT (see round-1 derivation):
//   out_row = FWHT( h0 .* s .* rint(clamp(FWHT(x_row) .* h0 / s, -Qn, Qp)) )
// with h0 = hadamard[0,:] = signs/sqrt(D).
//
// Round-2 change: all 11 butterfly stages are pure-VALU register butterflies;
// layout changes use XOR-swizzled LDS transposes (b128) instead of 6 shfl
// stages, cutting DS-pipe occupancy ~3x.
//
// Bit partition of element index j (11 bits):
//   layout A: comps=j[0:2], regs=j[8:11], lanes=j[2:8]   (global-coalesced)
//   layout B: comps=j[0:2], regs=j[2:5],  lanes=j[5:11]
//   layout C: comps=j[0:2], regs=j[5:8],  lanes=j[2:5],j[8:11]
// LDS swizzles (float index): addr1 = j ^ (j[5:8]<<2)  for A<->B
//                             addr2 = j ^ (j[8:11]<<2) for B<->C
// Both give exactly 8 hits per bank per b128 wave op (the minimum) in all
// eight read/write patterns.

constexpr int D  = 2048;
constexpr int NR = 8;   // float4 regs per lane: 8 * 4 * 64 = 2048

#define LGKM0() __asm__ __volatile__("s_waitcnt lgkmcnt(0)" ::: "memory")

__device__ __forceinline__ void bfly(float4& a, float4& b) {
    float4 ta = a, tb = b;
    a.x = ta.x + tb.x; a.y = ta.y + tb.y; a.z = ta.z + tb.z; a.w = ta.w + tb.w;
    b.x = ta.x - tb.x; b.y = ta.y - tb.y; b.z = ta.z - tb.z; b.w = ta.w - tb.w;
}

// butterflies over the 3 register-index bits (whatever j-bits they carry)
__device__ __forceinline__ void reg_stages(float4 (&v)[NR]) {
    #pragma unroll
    for (int m = 1; m <= 4; m <<= 1) {
        #pragma unroll
        for (int r = 0; r < NR; ++r)
            if ((r & m) == 0) bfly(v[r], v[r | m]);
    }
}

// butterflies over j bits {0,1} (float4 components)
__device__ __forceinline__ void comp_stages(float4 (&v)[NR]) {
    #pragma unroll
    for (int r = 0; r < NR; ++r) {
        float a, b;
        a = v[r].x; b = v[r].y; v[r].x = a + b; v[r].y = a - b;   // bit 0
        a = v[r].z; b = v[r].w; v[r].z = a + b; v[r].w = a - b;
        a = v[r].x; b = v[r].z; v[r].x = a + b; v[r].z = a - b;   // bit 1
        a = v[r].y; b = v[r].w; v[r].y = a + b; v[r].w = a - b;
    }
}

__device__ __forceinline__ float quant1(float xh, float h0, float s, float inv_s,
                                        float nqn, float qp) {
    float u = xh * h0 * inv_s;
    u = fminf(fmaxf(u, nqn), qp);
    float q = rintf(u);                       // round half-to-even (jnp.round)
    return q * (s * h0);                      // *s, fold the second h0 multiply
}

__global__ __launch_bounds__(256) void lsq_fwht_kernel(
    const float* __restrict__ x,
    const float* __restrict__ scale,
    const float* __restrict__ hadamard,
    const int*   __restrict__ qn_p,
    const int*   __restrict__ qp_p,
    const int*   __restrict__ ne_p,
    float*       __restrict__ out,
    int rows)
{
    __shared__ float smem[4][D];              // 8 KiB per wave, wave-private

    const int lane = threadIdx.x & 63;
    const int wave = threadIdx.x >> 6;
    const int row  = blockIdx.x * 4 + wave;   // one wave per row
    if (row >= rows) return;

    float* lds = smem[wave];
    const int llo = lane & 7;
    const int lhi = lane >> 3;

    // LSQ scale trick (forward value == scale), fp32 rounding as in reference
    const float sc    = scale[0];
    const float qp    = (float)qp_p[0];
    const float nqn   = -(float)qn_p[0];
    const float gs    = 1.0f / sqrtf((float)ne_p[0] * qp);
    const float bw    = sc * gs;
    const float s     = (sc - bw) + bw;
    const float inv_s = 1.0f / s;

    // ---- load x in layout A: j = r*256 + lane*4 + c ----
    float4 v[NR];
    {
        const float4* x4 = reinterpret_cast<const float4*>(x + (size_t)row * D) + lane;
        #pragma unroll
        for (int r = 0; r < NR; ++r) v[r] = x4[(size_t)r * 64];
    }
    // ---- load h0 in layout C: j = lhi*256 + r*32 + llo*4 + c ----
    float4 h[NR];
    {
        const float4* h4 = reinterpret_cast<const float4*>(hadamard);
        #pragma unroll
        for (int r = 0; r < NR; ++r) h[r] = h4[lhi * 64 + r * 8 + llo];
    }

    // swizzled address bases (float indices)
    const int wA  = (lane * 4) ^ (lhi << 2);                // + r*256   (A, addr1)
    const int rBb = lhi * 256 + llo * 32;                   // B base
    const int rCb = lhi * 256 + ((llo * 4) ^ (lhi << 2));   // + r*32    (C, addr2)

    // ================= FWHT #1 =================
    comp_stages(v);                                         // bits 0,1
    reg_stages(v);                                          // bits 8,9,10
    // transpose A -> B (addr1)
    #pragma unroll
    for (int r = 0; r < NR; ++r)
        *reinterpret_cast<float4*>(lds + r * 256 + wA) = v[r];
    LGKM0();
    #pragma unroll
    for (int r = 0; r < NR; ++r)
        v[r] = *reinterpret_cast<const float4*>(lds + rBb + ((r * 4) ^ (llo << 2)));
    reg_stages(v);                                          // bits 2,3,4
    // transpose B -> C (addr2)
    #pragma unroll
    for (int r = 0; r < NR; ++r)
        *reinterpret_cast<float4*>(lds + rBb + ((r * 4) ^ (lhi << 2))) = v[r];
    LGKM0();
    #pragma unroll
    for (int r = 0; r < NR; ++r)
        v[r] = *reinterpret_cast<const float4*>(lds + rCb + r * 32);
    reg_stages(v);                                          // bits 5,6,7

    // ================= quantize (layout C) =================
    #pragma unroll
    for (int r = 0; r < NR; ++r) {
        v[r].x = quant1(v[r].x, h[r].x, s, inv_s, nqn, qp);
        v[r].y = quant1(v[r].y, h[r].y, s, inv_s, nqn, qp);
        v[r].z = quant1(v[r].z, h[r].z, s, inv_s, nqn, qp);
        v[r].w = quant1(v[r].w, h[r].w, s, inv_s, nqn, qp);
    }

    // ================= FWHT #2 =================
    reg_stages(v);                                          // bits 5,6,7
    // transpose C -> B (addr2)
    #pragma unroll
    for (int r = 0; r < NR; ++r)
        *reinterpret_cast<float4*>(lds + rCb + r * 32) = v[r];
    LGKM0();
    #pragma unroll
    for (int r = 0; r < NR; ++r)
        v[r] = *reinterpret_cast<const float4*>(lds + rBb + ((r * 4) ^ (lhi << 2)));
    reg_stages(v);                                          // bits 2,3,4
    // transpose B -> A (addr1)
    #pragma unroll
    for (int r = 0; r < NR; ++r)
        *reinterpret_cast<float4*>(lds + rBb + ((r * 4) ^ (llo << 2))) = v[r];
    LGKM0();
    #pragma unroll
    for (int r = 0; r < NR; ++r)
        v[r] = *reinterpret_cast<const float4*>(lds + r * 256 + wA);
    reg_stages(v);                                          // bits 8,9,10
    comp_stages(v);                                         // bits 0,1

    // ---- store (layout A, coalesced) ----
    {
        float4* y4 = reinterpret_cast<float4*>(out + (size_t)row * D) + lane;
        #pragma unroll
        for (int r = 0; r < NR; ++r) y4[(size_t)r * 64] = v[r];
    }
}

extern "C" void kernel_launch(void* const* d_in, const int* in_sizes, int n_in,
                              void* d_out, int out_size, void* d_ws, size_t ws_size,
                              hipStream_t stream) {
    const float* x        = (const float*)d_in[0];
    const float* scale    = (const float*)d_in[1];
    const float* hadamard = (const float*)d_in[2];
    const int*   Qn       = (const int*)d_in[3];
    const int*   Qp       = (const int*)d_in[4];
    const int*   ne       = (const int*)d_in[5];
    float*       out      = (float*)d_out;

    const int rows = in_sizes[0] / D;          // 16384 for B=4,S=4096
    const int grid = (rows + 3) / 4;           // 4 waves (rows) per block

    lsq_fwht_kernel<<<grid, 256, 0, stream>>>(x, scale, hadamard, Qn, Qp, ne,
                                              out, rows);
}